// Round 1
// baseline (207.633 us; speedup 1.0000x reference)
//
#include <hip/hip_runtime.h>
#include <hip/hip_bf16.h>

// Scaled dot-product attention, B=16, S=2048, D=128, fp32 in/out.
// bf16 MFMA for QK^T and PV; fp32 online softmax.

#define NB 16
#define NS 2048
#define ND 128
#define ATTN_SCALE 0.08838834764831845f   // 1/sqrt(128)

#define KVBLK 64
#define NWAVE 4
#define LDK (ND + 8)      // 136 shorts -> 272B row stride (multiple of 16B)
#define LDV (KVBLK + 8)   // 72 shorts  -> 144B row stride (multiple of 16B)
#define LDP (KVBLK + 8)

typedef __attribute__((ext_vector_type(8))) short bf16x8;
typedef __attribute__((ext_vector_type(4))) short short4v;
typedef __attribute__((ext_vector_type(4))) float f32x4;

__device__ __forceinline__ short f2bf(float f) {
    unsigned u = __builtin_bit_cast(unsigned, f);
    return (short)((u + 0x7fffu + ((u >> 16) & 1u)) >> 16);  // RNE
}

__global__ __launch_bounds__(256, 2)
void sdpa_fwd(const float* __restrict__ Qg, const float* __restrict__ Kg,
              const float* __restrict__ Vg, float* __restrict__ Og) {
    // K tile, row-major [kk][d]
    __shared__ __align__(16) short k_lds[KVBLK][LDK];
    // V tile, transposed [d][kk], kk-block XOR-swizzled by (d>>3)&7
    __shared__ __align__(16) short vT_lds[ND][LDV];
    // per-wave P relayout buffer [q][kk]
    __shared__ __align__(16) short p_lds[NWAVE][16][LDP];

    const int tid  = threadIdx.x;
    const int w    = tid >> 6;
    const int lane = tid & 63;
    const int lq   = lane & 15;   // fragment col (q for S^T, d for O)
    const int lg   = lane >> 4;   // lane group 0..3

    const int b  = blockIdx.y;
    const int q0 = blockIdx.x * (NWAVE * 16) + w * 16;

    // Q fragments: lane holds Q[q0+lq][kc*32 + lg*8 + 0..7] (A-layout data,
    // which is exactly the B-operand layout for S^T = K * Q^T).
    bf16x8 qf[4];
    {
        const float* qrow = Qg + ((size_t)b * NS + q0 + lq) * ND;
#pragma unroll
        for (int kc = 0; kc < 4; ++kc) {
            const float4* p = (const float4*)(qrow + kc * 32 + lg * 8);
            float4 x0 = p[0], x1 = p[1];
            bf16x8 f;
            f[0] = f2bf(x0.x); f[1] = f2bf(x0.y); f[2] = f2bf(x0.z); f[3] = f2bf(x0.w);
            f[4] = f2bf(x1.x); f[5] = f2bf(x1.y); f[6] = f2bf(x1.z); f[7] = f2bf(x1.w);
            qf[kc] = f;
        }
    }

    f32x4 acc[8];
#pragma unroll
    for (int i = 0; i < 8; ++i) acc[i] = {0.f, 0.f, 0.f, 0.f};
    float m_run = -__builtin_inff();
    float l_run = 0.f;

    const float* Kb = Kg + (size_t)b * NS * ND;
    const float* Vb = Vg + (size_t)b * NS * ND;

    for (int t = 0; t < NS / KVBLK; ++t) {
        __syncthreads();   // previous tile fully consumed
        // ---- stage K (row-major) and V (transposed, swizzled) as bf16 ----
#pragma unroll
        for (int it = 0; it < 8; ++it) {
            int idx = it * 256 + tid;
            int row = idx >> 5;            // kv row 0..63
            int c4  = (idx & 31) << 2;     // d 0..124 step 4
            const float* srck = Kb + (size_t)(t * KVBLK + row) * ND + c4;
            float4 kv = *(const float4*)srck;
            short4v ks = { f2bf(kv.x), f2bf(kv.y), f2bf(kv.z), f2bf(kv.w) };
            *(short4v*)&k_lds[row][c4] = ks;
            const float* srcv = Vb + (size_t)(t * KVBLK + row) * ND + c4;
            float4 vv = *(const float4*)srcv;
            float vf[4] = { vv.x, vv.y, vv.z, vv.w };
#pragma unroll
            for (int di = 0; di < 4; ++di) {
                int d = c4 + di;
                int swz = (d >> 3) & 7;
                vT_lds[d][(((row >> 3) ^ swz) << 3) + (row & 7)] = f2bf(vf[di]);
            }
        }
        __syncthreads();

        // ---- S^T[kk][q] = K * Q^T : 4 kk-blocks x 4 K-dim chunks ----
        f32x4 sacc[4];
#pragma unroll
        for (int kb = 0; kb < 4; ++kb) {
            f32x4 a = {0.f, 0.f, 0.f, 0.f};
#pragma unroll
            for (int kc = 0; kc < 4; ++kc) {
                bf16x8 kf = *(const bf16x8*)&k_lds[kb * 16 + lq][kc * 32 + lg * 8];
                a = __builtin_amdgcn_mfma_f32_16x16x32_bf16(kf, qf[kc], a, 0, 0, 0);
            }
            sacc[kb] = a;
        }

        // ---- online softmax: lane holds S^T[kb*16 + lg*4 + r][q=lq] ----
        float sv[16], tmax = -__builtin_inff();
#pragma unroll
        for (int kb = 0; kb < 4; ++kb)
#pragma unroll
            for (int r = 0; r < 4; ++r) {
                float s = sacc[kb][r] * ATTN_SCALE;
                sv[kb * 4 + r] = s;
                tmax = fmaxf(tmax, s);
            }
        tmax = fmaxf(tmax, __shfl_xor(tmax, 16));
        tmax = fmaxf(tmax, __shfl_xor(tmax, 32));
        float m_new = fmaxf(m_run, tmax);
        float alpha = __expf(m_run - m_new);   // expf(-inf)=0 on first tile
        float tsum = 0.f;
        short pb16[16];
#pragma unroll
        for (int i = 0; i < 16; ++i) {
            float p = __expf(sv[i] - m_new);
            tsum += p;
            pb16[i] = f2bf(p);
        }
        tsum += __shfl_xor(tsum, 16);
        tsum += __shfl_xor(tsum, 32);
        l_run = l_run * alpha + tsum;
        m_run = m_new;

        // rescale O (O rows are q = lg*4 + r; alpha lives at lane q of group 0)
        float af[4];
#pragma unroll
        for (int r = 0; r < 4; ++r) af[r] = __shfl(alpha, lg * 4 + r);
#pragma unroll
        for (int d = 0; d < 8; ++d)
#pragma unroll
            for (int r = 0; r < 4; ++r) acc[d][r] *= af[r];

        // ---- P to LDS (per-wave), re-read in A-fragment layout ----
#pragma unroll
        for (int kb = 0; kb < 4; ++kb) {
            short4v ps = { pb16[kb*4+0], pb16[kb*4+1], pb16[kb*4+2], pb16[kb*4+3] };
            *(short4v*)&p_lds[w][lq][kb * 16 + lg * 4] = ps;
        }
        bf16x8 pa0 = *(const bf16x8*)&p_lds[w][lq][lg * 8];
        bf16x8 pa1 = *(const bf16x8*)&p_lds[w][lq][32 + lg * 8];

        // ---- O[q][d] += P * V ----
#pragma unroll
        for (int d = 0; d < 8; ++d) {
            int dd  = d * 16 + lq;
            int swz = (dd >> 3) & 7;
            bf16x8 v0 = *(const bf16x8*)&vT_lds[dd][((lg ^ swz) & 7) << 3];
            acc[d] = __builtin_amdgcn_mfma_f32_16x16x32_bf16(pa0, v0, acc[d], 0, 0, 0);
            bf16x8 v1 = *(const bf16x8*)&vT_lds[dd][(((4 + lg) ^ swz) & 7) << 3];
            acc[d] = __builtin_amdgcn_mfma_f32_16x16x32_bf16(pa1, v1, acc[d], 0, 0, 0);
        }
    }

    // ---- epilogue: normalize by row sum, store fp32 ----
    float lr[4];
#pragma unroll
    for (int r = 0; r < 4; ++r) lr[r] = 1.f / __shfl(l_run, lg * 4 + r);
    float* orow = Og + ((size_t)b * NS + q0) * ND;
#pragma unroll
    for (int d = 0; d < 8; ++d)
#pragma unroll
        for (int r = 0; r < 4; ++r)
            orow[(size_t)(lg * 4 + r) * ND + d * 16 + lq] = acc[d][r] * lr[r];
}

extern "C" void kernel_launch(void* const* d_in, const int* in_sizes, int n_in,
                              void* d_out, int out_size, void* d_ws, size_t ws_size,
                              hipStream_t stream) {
    const float* Q = (const float*)d_in[0];
    const float* K = (const float*)d_in[1];
    const float* V = (const float*)d_in[2];
    float* O = (float*)d_out;
    (void)in_sizes; (void)n_in; (void)out_size; (void)d_ws; (void)ws_size;
    dim3 grid(NS / (NWAVE * 16), NB);
    sdpa_fwd<<<grid, 256, 0, stream>>>(Q, K, V, O);
}

// Round 2
// 81.113 us; speedup vs baseline: 2.5598x; 2.5598x over previous
//
#include <hip/hip_runtime.h>
#include <hip/hip_bf16.h>

// Scaled dot-product attention, B=16, S=2048, D=128, fp32 in/out.
// Two kernels:
//  1) prep_kv: convert K,V to bf16 once, store per-KV-tile pre-swizzled LDS
//     images (K row-major 64x256B, V transposed 128x128B, both XOR-swizzled
//     byte ^= (row&7)<<4) into d_ws.
//  2) sdpa_fwd: flash attention; stages tile images with linear
//     global_load_lds (double-buffered, prefetch), bf16 MFMA, fp32 softmax.

#define NB 16
#define NS 2048
#define ND 128
#define ATTN_SCALE 0.08838834764831845f   // 1/sqrt(128)

#define KVBLK 64
#define NT (NS / KVBLK)          // 32 KV tiles per batch
#define NWAVE 4
#define LDP 72                   // P buffer pad
#define IMGB 32768               // per-tile image: K 16KB + V 16KB

typedef __attribute__((ext_vector_type(8))) short bf16x8;
typedef __attribute__((ext_vector_type(4))) short short4v;
typedef __attribute__((ext_vector_type(4))) float f32x4;

__device__ __forceinline__ short f2bf(float f) {
    unsigned u = __builtin_bit_cast(unsigned, f);
    return (short)((u + 0x7fffu + ((u >> 16) & 1u)) >> 16);  // RNE
}

__device__ __forceinline__ void gll16(const void* g, void* l) {
    __builtin_amdgcn_global_load_lds(
        (const __attribute__((address_space(1))) uint32_t*)g,
        (__attribute__((address_space(3))) uint32_t*)l, 16, 0, 0);
}

// ---------------- pre-pass: build swizzled bf16 tile images ----------------
__global__ __launch_bounds__(256, 2)
void prep_kv(const float* __restrict__ Kg, const float* __restrict__ Vg,
             uint8_t* __restrict__ ws) {
    __shared__ __align__(16) uint8_t img[IMGB];
    const int tid = threadIdx.x;
    const int t = blockIdx.x, b = blockIdx.y;
    const float* Kb = Kg + ((size_t)b * NS + (size_t)t * KVBLK) * ND;
    const float* Vb = Vg + ((size_t)b * NS + (size_t)t * KVBLK) * ND;
#pragma unroll
    for (int it = 0; it < 8; ++it) {
        int idx = it * 256 + tid;
        int r  = idx >> 5;            // kv row 0..63
        int c4 = (idx & 31) << 2;     // d 0..124 step 4
        // K image: element (r, d) at byte r*256 + ((2d) ^ ((r&7)<<4))
        float4 kvv = *(const float4*)(Kb + (size_t)r * ND + c4);
        short4v ks = { f2bf(kvv.x), f2bf(kvv.y), f2bf(kvv.z), f2bf(kvv.w) };
        *(short4v*)&img[r * 256 + ((c4 * 2) ^ ((r & 7) << 4))] = ks;
        // V image (transposed): element (kk=r, d) at byte
        //   16384 + d*128 + ((2r) ^ ((d&7)<<4))
        float4 vv = *(const float4*)(Vb + (size_t)r * ND + c4);
        float vf[4] = { vv.x, vv.y, vv.z, vv.w };
#pragma unroll
        for (int di = 0; di < 4; ++di) {
            int d = c4 + di;
            *(short*)&img[16384 + d * 128 + ((r * 2) ^ ((d & 7) << 4))] = f2bf(vf[di]);
        }
    }
    __syncthreads();
    // coalesced copy-out of the finished image
    float4* dst = (float4*)(ws + (size_t)(b * NT + t) * IMGB);
    const float4* srcl = (const float4*)img;
#pragma unroll
    for (int j = 0; j < 8; ++j)
        dst[j * 256 + tid] = srcl[j * 256 + tid];
}

// ---------------- main attention kernel ----------------
__global__ __launch_bounds__(256, 2)
void sdpa_fwd(const float* __restrict__ Qg, const uint8_t* __restrict__ ws,
              float* __restrict__ Og) {
    __shared__ __align__(16) uint8_t kv[2][IMGB];          // double-buffered images
    __shared__ __align__(16) short p_lds[NWAVE][16][LDP];  // per-wave P relayout

    const int tid  = threadIdx.x;
    const int w    = tid >> 6;
    const int lane = tid & 63;
    const int lq   = lane & 15;
    const int lg   = lane >> 4;
    const int xr   = (lq & 7) << 4;   // XOR swizzle for this lane's LDS rows

    const int b  = blockIdx.y;
    const int q0 = blockIdx.x * (NWAVE * 16) + w * 16;

    // Q fragments (fp32 load + convert, once per block)
    bf16x8 qf[4];
    {
        const float* qrow = Qg + ((size_t)b * NS + q0 + lq) * ND;
#pragma unroll
        for (int kc = 0; kc < 4; ++kc) {
            const float4* p = (const float4*)(qrow + kc * 32 + lg * 8);
            float4 x0 = p[0], x1 = p[1];
            bf16x8 f;
            f[0] = f2bf(x0.x); f[1] = f2bf(x0.y); f[2] = f2bf(x0.z); f[3] = f2bf(x0.w);
            f[4] = f2bf(x1.x); f[5] = f2bf(x1.y); f[6] = f2bf(x1.z); f[7] = f2bf(x1.w);
            qf[kc] = f;
        }
    }

    f32x4 acc[8];
#pragma unroll
    for (int i = 0; i < 8; ++i) acc[i] = {0.f, 0.f, 0.f, 0.f};
    float m_run = -__builtin_inff();
    float l_run = 0.f;

    const uint8_t* wsb = ws + (size_t)b * NT * IMGB;

    // stage tile t's 32KB image into buffer `bf` (linear global_load_lds)
    auto stage = [&](int bfi, int t) {
        const uint8_t* src = wsb + (size_t)t * IMGB + (size_t)(w * 8192 + lane * 16);
        uint8_t* dst = &kv[bfi][w * 8192];
#pragma unroll
        for (int it = 0; it < 8; ++it)
            gll16(src + it * 1024, dst + it * 1024);
    };

    int buf = 0;
    stage(0, 0);
    __syncthreads();

    for (int t = 0; t < NT; ++t) {
        if (t + 1 < NT) stage(buf ^ 1, t + 1);   // prefetch next tile

        const uint8_t* kb_ = kv[buf];
        const uint8_t* vb_ = kv[buf] + 16384;

        // ---- S^T = K * Q^T ----
        f32x4 sacc[4];
#pragma unroll
        for (int kb = 0; kb < 4; ++kb) {
            f32x4 a = {0.f, 0.f, 0.f, 0.f};
            int rowb = (kb * 16 + lq) * 256;
#pragma unroll
            for (int kc = 0; kc < 4; ++kc) {
                bf16x8 kf = *(const bf16x8*)(kb_ + rowb + ((kc * 64 + lg * 16) ^ xr));
                a = __builtin_amdgcn_mfma_f32_16x16x32_bf16(kf, qf[kc], a, 0, 0, 0);
            }
            sacc[kb] = a;
        }

        // ---- online softmax (lane holds S^T[kb*16+lg*4+r][q=lq]) ----
        float sv[16], tmax = -__builtin_inff();
#pragma unroll
        for (int kb = 0; kb < 4; ++kb)
#pragma unroll
            for (int r = 0; r < 4; ++r) {
                float s = sacc[kb][r] * ATTN_SCALE;
                sv[kb * 4 + r] = s;
                tmax = fmaxf(tmax, s);
            }
        tmax = fmaxf(tmax, __shfl_xor(tmax, 16));
        tmax = fmaxf(tmax, __shfl_xor(tmax, 32));
        float m_new = fmaxf(m_run, tmax);
        float alpha = __expf(m_run - m_new);
        float tsum = 0.f;
        short pb16[16];
#pragma unroll
        for (int i = 0; i < 16; ++i) {
            float p = __expf(sv[i] - m_new);
            tsum += p;
            pb16[i] = f2bf(p);
        }
        tsum += __shfl_xor(tsum, 16);
        tsum += __shfl_xor(tsum, 32);
        l_run = l_run * alpha + tsum;
        m_run = m_new;

        float af[4];
#pragma unroll
        for (int r = 0; r < 4; ++r) af[r] = __shfl(alpha, lg * 4 + r);
#pragma unroll
        for (int d = 0; d < 8; ++d)
#pragma unroll
            for (int r = 0; r < 4; ++r) acc[d][r] *= af[r];

        // ---- P relayout through per-wave LDS ----
#pragma unroll
        for (int kb = 0; kb < 4; ++kb) {
            short4v ps = { pb16[kb*4+0], pb16[kb*4+1], pb16[kb*4+2], pb16[kb*4+3] };
            *(short4v*)&p_lds[w][lq][kb * 16 + lg * 4] = ps;
        }
        bf16x8 pa0 = *(const bf16x8*)&p_lds[w][lq][lg * 8];
        bf16x8 pa1 = *(const bf16x8*)&p_lds[w][lq][32 + lg * 8];

        // ---- O += P * V ----
#pragma unroll
        for (int d = 0; d < 8; ++d) {
            int rb = (d * 16 + lq) * 128;
            bf16x8 v0 = *(const bf16x8*)(vb_ + rb + ((lg * 16) ^ xr));
            acc[d] = __builtin_amdgcn_mfma_f32_16x16x32_bf16(pa0, v0, acc[d], 0, 0, 0);
            bf16x8 v1 = *(const bf16x8*)(vb_ + rb + ((64 + lg * 16) ^ xr));
            acc[d] = __builtin_amdgcn_mfma_f32_16x16x32_bf16(pa1, v1, acc[d], 0, 0, 0);
        }

        __syncthreads();   // drains vmcnt(0) (prefetch) + barrier
        buf ^= 1;
    }

    // ---- epilogue ----
    float lr[4];
#pragma unroll
    for (int r = 0; r < 4; ++r) lr[r] = 1.f / __shfl(l_run, lg * 4 + r);
    float* orow = Og + ((size_t)b * NS + q0) * ND;
#pragma unroll
    for (int d = 0; d < 8; ++d)
#pragma unroll
        for (int r = 0; r < 4; ++r)
            orow[(size_t)(lg * 4 + r) * ND + d * 16 + lq] = acc[d][r] * lr[r];
}

extern "C" void kernel_launch(void* const* d_in, const int* in_sizes, int n_in,
                              void* d_out, int out_size, void* d_ws, size_t ws_size,
                              hipStream_t stream) {
    const float* Q = (const float*)d_in[0];
    const float* K = (const float*)d_in[1];
    const float* V = (const float*)d_in[2];
    float* O = (float*)d_out;
    (void)in_sizes; (void)n_in; (void)out_size; (void)ws_size;
    uint8_t* ws = (uint8_t*)d_ws;
    prep_kv<<<dim3(NT, NB), 256, 0, stream>>>(K, V, ws);
    sdpa_fwd<<<dim3(NS / (NWAVE * 16), NB), 256, 0, stream>>>(Q, ws, O);
}

// Round 3
// 79.811 us; speedup vs baseline: 2.6016x; 1.0163x over previous
//
#include <hip/hip_runtime.h>
#include <hip/hip_bf16.h>

// Scaled dot-product attention, B=16, S=2048, D=128, fp32 in/out.
//  prep_kv: K,V -> bf16 once; per-tile pre-swizzled LDS images in d_ws.
//  sdpa_fwd: flash attention; linear global_load_lds double-buffered staging,
//  bf16 MFMA, fp32 online softmax in exp2 domain, in-register P relayout.

#define NB 16
#define NS 2048
#define ND 128
#define KVBLK 64
#define NT (NS / KVBLK)          // 32 KV tiles per batch
#define NWAVE 4
#define IMGB 32768               // per-tile image: K 16KB + V 16KB
// Q pre-scale: (1/sqrt(128)) * log2(e)  -> softmax in exp2 domain
#define QSC (0.08838834764831845f * 1.4426950408889634f)

typedef __attribute__((ext_vector_type(8))) short bf16x8;
typedef __attribute__((ext_vector_type(4))) short short4v;
typedef __attribute__((ext_vector_type(4))) float f32x4;
typedef __attribute__((ext_vector_type(4))) int int4v;

__device__ __forceinline__ short f2bf(float f) {
    unsigned u = __builtin_bit_cast(unsigned, f);
    return (short)((u + 0x7fffu + ((u >> 16) & 1u)) >> 16);  // RNE
}

#if __has_builtin(__builtin_amdgcn_exp2f)
#define EXP2F(x) __builtin_amdgcn_exp2f(x)
#else
#define EXP2F(x) __expf((x) * 0.6931471805599453f)
#endif

__device__ __forceinline__ void gll16(const void* g, void* l) {
    __builtin_amdgcn_global_load_lds(
        (const __attribute__((address_space(1))) uint32_t*)g,
        (__attribute__((address_space(3))) uint32_t*)l, 16, 0, 0);
}

// ---------------- pre-pass: build swizzled bf16 tile images ----------------
__global__ __launch_bounds__(256, 2)
void prep_kv(const float* __restrict__ Kg, const float* __restrict__ Vg,
             uint8_t* __restrict__ ws) {
    __shared__ __align__(16) uint8_t img[IMGB];
    const int tid = threadIdx.x;
    const int t = blockIdx.x, b = blockIdx.y;
    const float* Kb = Kg + ((size_t)b * NS + (size_t)t * KVBLK) * ND;
    const float* Vb = Vg + ((size_t)b * NS + (size_t)t * KVBLK) * ND;
#pragma unroll
    for (int it = 0; it < 8; ++it) {
        int idx = it * 256 + tid;
        int r  = idx >> 5;            // kv row 0..63
        int c4 = (idx & 31) << 2;     // d 0..124 step 4
        // K image: element (r, d) at byte r*256 + ((2d) ^ ((r&7)<<4))
        float4 kvv = *(const float4*)(Kb + (size_t)r * ND + c4);
        short4v ks = { f2bf(kvv.x), f2bf(kvv.y), f2bf(kvv.z), f2bf(kvv.w) };
        *(short4v*)&img[r * 256 + ((c4 * 2) ^ ((r & 7) << 4))] = ks;
        // V image (transposed): (kk=r, d) at byte 16384 + d*128 + ((2r)^((d&7)<<4))
        float4 vv = *(const float4*)(Vb + (size_t)r * ND + c4);
        float vf[4] = { vv.x, vv.y, vv.z, vv.w };
#pragma unroll
        for (int di = 0; di < 4; ++di) {
            int d = c4 + di;
            *(short*)&img[16384 + d * 128 + ((r * 2) ^ ((d & 7) << 4))] = f2bf(vf[di]);
        }
    }
    __syncthreads();
    float4* dst = (float4*)(ws + (size_t)(b * NT + t) * IMGB);
    const float4* srcl = (const float4*)img;
#pragma unroll
    for (int j = 0; j < 8; ++j)
        dst[j * 256 + tid] = srcl[j * 256 + tid];
}

// ---------------- main attention kernel ----------------
__global__ __launch_bounds__(256, 2)
void sdpa_fwd(const float* __restrict__ Qg, const uint8_t* __restrict__ ws,
              float* __restrict__ Og) {
    __shared__ __align__(16) uint8_t kv[2][IMGB];   // double-buffered tile images

    const int tid  = threadIdx.x;
    const int w    = tid >> 6;
    const int lane = tid & 63;
    const int lq   = lane & 15;
    const int lg   = lane >> 4;
    const int xr   = (lq & 7) << 4;   // XOR swizzle for this lane's LDS rows

    const int b  = blockIdx.y;
    const int q0 = blockIdx.x * (NWAVE * 16) + w * 16;

    // Q fragments, pre-scaled by 1/sqrt(D)*log2(e)
    bf16x8 qf[4];
    {
        const float* qrow = Qg + ((size_t)b * NS + q0 + lq) * ND;
#pragma unroll
        for (int kc = 0; kc < 4; ++kc) {
            const float4* p = (const float4*)(qrow + kc * 32 + lg * 8);
            float4 x0 = p[0], x1 = p[1];
            bf16x8 f;
            f[0] = f2bf(x0.x * QSC); f[1] = f2bf(x0.y * QSC);
            f[2] = f2bf(x0.z * QSC); f[3] = f2bf(x0.w * QSC);
            f[4] = f2bf(x1.x * QSC); f[5] = f2bf(x1.y * QSC);
            f[6] = f2bf(x1.z * QSC); f[7] = f2bf(x1.w * QSC);
            qf[kc] = f;
        }
    }

    f32x4 acc[8];
#pragma unroll
    for (int i = 0; i < 8; ++i) acc[i] = {0.f, 0.f, 0.f, 0.f};
    float m_run = -__builtin_inff();
    float l_run = 0.f;

    const uint8_t* wsb = ws + (size_t)b * NT * IMGB;

    auto stage = [&](int bfi, int t) {
        const uint8_t* src = wsb + (size_t)t * IMGB + (size_t)(w * 8192 + lane * 16);
        uint8_t* dst = &kv[bfi][w * 8192];
#pragma unroll
        for (int it = 0; it < 8; ++it)
            gll16(src + it * 1024, dst + it * 1024);
    };

    int buf = 0;
    stage(0, 0);
    __syncthreads();

    for (int t = 0; t < NT; ++t) {
        if (t + 1 < NT) stage(buf ^ 1, t + 1);   // async prefetch next tile

        const uint8_t* kb_ = kv[buf];
        const uint8_t* vb_ = kv[buf] + 16384;

        // ---- S^T = K * Q^T  (kc outer so XOR addr math hoists; kb via imm) ----
        f32x4 sacc[4];
#pragma unroll
        for (int i = 0; i < 4; ++i) sacc[i] = {0.f, 0.f, 0.f, 0.f};
        __builtin_amdgcn_s_setprio(1);
#pragma unroll
        for (int kc = 0; kc < 4; ++kc) {
            const uint8_t* kbase = kb_ + lq * 256 + ((kc * 64 + lg * 16) ^ xr);
#pragma unroll
            for (int kb = 0; kb < 4; ++kb) {
                bf16x8 kf = *(const bf16x8*)(kbase + kb * 4096);
                sacc[kb] = __builtin_amdgcn_mfma_f32_16x16x32_bf16(kf, qf[kc], sacc[kb], 0, 0, 0);
            }
        }
        __builtin_amdgcn_s_setprio(0);

        // ---- online softmax in exp2 domain (lane: S^T[kb*16+lg*4+r][q=lq]) ----
        float pv[16], tmax = -__builtin_inff();
#pragma unroll
        for (int kb = 0; kb < 4; ++kb)
#pragma unroll
            for (int r = 0; r < 4; ++r) {
                float s = sacc[kb][r];
                pv[kb * 4 + r] = s;
                tmax = fmaxf(tmax, s);
            }
        tmax = fmaxf(tmax, __shfl_xor(tmax, 16));
        tmax = fmaxf(tmax, __shfl_xor(tmax, 32));

        if (__any(tmax > m_run + 8.0f)) {          // defer-max (T13)
            float m_new = fmaxf(m_run, tmax);
            float alpha = EXP2F(m_run - m_new);
            m_run = m_new;
            l_run *= alpha;
            float af[4];
#pragma unroll
            for (int r = 0; r < 4; ++r) af[r] = __shfl(alpha, lg * 4 + r);
#pragma unroll
            for (int d = 0; d < 8; ++d)
#pragma unroll
                for (int r = 0; r < 4; ++r) acc[d][r] *= af[r];
        }

        float tsum = 0.f;
#pragma unroll
        for (int i = 0; i < 16; ++i) {
            pv[i] = EXP2F(pv[i] - m_run);
            tsum += pv[i];
        }
        tsum += __shfl_xor(tsum, 16);
        tsum += __shfl_xor(tsum, 32);
        l_run += tsum;

        // ---- pack P to bf16 words (cvt_pk) + in-register relayout to A-frag ----
        int W[8];
#pragma unroll
        for (int m = 0; m < 8; ++m) {
            int i0 = (m >> 1) * 4 + (m & 1) * 2;   // W[m] = pack(pv[i0], pv[i0+1])
            asm("v_cvt_pk_bf16_f32 %0, %1, %2" : "=v"(W[m]) : "v"(pv[i0]), "v"(pv[i0 + 1]));
        }
        const bool hi = (lg & 2) != 0;
        int4v A0, A1;
#pragma unroll
        for (int j = 0; j < 4; ++j) {
            int srcl = lq + (((lg & 1) * 2 + (j >> 1)) << 4);
            int t0 = __shfl(W[j & 1], srcl);
            int t1 = __shfl(W[2 + (j & 1)], srcl);
            A0[j] = hi ? t1 : t0;
            int u0 = __shfl(W[4 + (j & 1)], srcl);
            int u1 = __shfl(W[6 + (j & 1)], srcl);
            A1[j] = hi ? u1 : u0;
        }
        bf16x8 pa0 = __builtin_bit_cast(bf16x8, A0);
        bf16x8 pa1 = __builtin_bit_cast(bf16x8, A1);

        // ---- O += P * V  (addr XOR hoisted, d via imm offsets) ----
        const uint8_t* v0b = vb_ + lq * 128 + ((lg * 16) ^ xr);
        const uint8_t* v1b = vb_ + lq * 128 + ((64 + lg * 16) ^ xr);
        __builtin_amdgcn_s_setprio(1);
#pragma unroll
        for (int d = 0; d < 8; ++d) {
            bf16x8 v0 = *(const bf16x8*)(v0b + d * 2048);
            acc[d] = __builtin_amdgcn_mfma_f32_16x16x32_bf16(pa0, v0, acc[d], 0, 0, 0);
            bf16x8 v1 = *(const bf16x8*)(v1b + d * 2048);
            acc[d] = __builtin_amdgcn_mfma_f32_16x16x32_bf16(pa1, v1, acc[d], 0, 0, 0);
        }
        __builtin_amdgcn_s_setprio(0);

        __syncthreads();   // next tile's image now resident
        buf ^= 1;
    }

    // ---- epilogue ----
    float lr[4];
#pragma unroll
    for (int r = 0; r < 4; ++r) lr[r] = 1.f / __shfl(l_run, lg * 4 + r);
    float* orow = Og + ((size_t)b * NS + q0) * ND;
#pragma unroll
    for (int d = 0; d < 8; ++d)
#pragma unroll
        for (int r = 0; r < 4; ++r)
            orow[(size_t)(lg * 4 + r) * ND + d * 16 + lq] = acc[d][r] * lr[r];
}

extern "C" void kernel_launch(void* const* d_in, const int* in_sizes, int n_in,
                              void* d_out, int out_size, void* d_ws, size_t ws_size,
                              hipStream_t stream) {
    const float* Q = (const float*)d_in[0];
    const float* K = (const float*)d_in[1];
    const float* V = (const float*)d_in[2];
    float* O = (float*)d_out;
    (void)in_sizes; (void)n_in; (void)out_size; (void)ws_size;
    uint8_t* ws = (uint8_t*)d_ws;
    prep_kv<<<dim3(NT, NB), 256, 0, stream>>>(K, V, ws);
    sdpa_fwd<<<dim3(NS / (NWAVE * 16), NB), 256, 0, stream>>>(Q, ws, O);
}

// Round 5
// 75.880 us; speedup vs baseline: 2.7363x; 1.0518x over previous
//
#include <hip/hip_runtime.h>
#include <hip/hip_bf16.h>

// Scaled dot-product attention, B=16, S=2048, D=128, fp32 in/out.
//  prep_kv: K,V -> bf16 once; per-tile pre-swizzled LDS images in d_ws.
//  sdpa_fwd: 32x32 MFMA flash attention, 4 waves x 32 q-rows, swapped QK^T,
//  fully in-register softmax (cvt_pk + shfl_xor(32) relayout), linear
//  global_load_lds double-buffered staging.

#define NB 16
#define NS 2048
#define ND 128
#define KVBLK 64
#define NT (NS / KVBLK)          // 32 KV tiles per batch
#define IMGB 32768               // per-tile image: K 16KB + V 16KB
// Q pre-scale: (1/sqrt(128)) * log2(e)  -> softmax in exp2 domain
#define QSC (0.08838834764831845f * 1.4426950408889634f)

typedef __attribute__((ext_vector_type(8))) short bf16x8;
typedef __attribute__((ext_vector_type(4))) short short4v;
typedef __attribute__((ext_vector_type(16))) float f32x16;
typedef __attribute__((ext_vector_type(4))) int int4v;

__device__ __forceinline__ short f2bf(float f) {
    unsigned u = __builtin_bit_cast(unsigned, f);
    return (short)((u + 0x7fffu + ((u >> 16) & 1u)) >> 16);  // RNE
}

#if __has_builtin(__builtin_amdgcn_exp2f)
#define EXP2F(x) __builtin_amdgcn_exp2f(x)
#else
#define EXP2F(x) __expf((x) * 0.6931471805599453f)
#endif

__device__ __forceinline__ void gll16(const void* g, void* l) {
    __builtin_amdgcn_global_load_lds(
        (const __attribute__((address_space(1))) uint32_t*)g,
        (__attribute__((address_space(3))) uint32_t*)l, 16, 0, 0);
}

// ---------------- pre-pass: build swizzled bf16 tile images ----------------
__global__ __launch_bounds__(256, 2)
void prep_kv(const float* __restrict__ Kg, const float* __restrict__ Vg,
             uint8_t* __restrict__ ws) {
    __shared__ __align__(16) uint8_t img[IMGB];
    const int tid = threadIdx.x;
    const int t = blockIdx.x, b = blockIdx.y;
    const float* Kb = Kg + ((size_t)b * NS + (size_t)t * KVBLK) * ND;
    const float* Vb = Vg + ((size_t)b * NS + (size_t)t * KVBLK) * ND;
#pragma unroll
    for (int it = 0; it < 8; ++it) {
        int idx = it * 256 + tid;
        int r  = idx >> 5;            // kv row 0..63
        int c4 = (idx & 31) << 2;     // d 0..124 step 4
        // K image: element (r, d) at byte r*256 + ((2d) ^ ((r&7)<<4))
        float4 kvv = *(const float4*)(Kb + (size_t)r * ND + c4);
        short4v ks = { f2bf(kvv.x), f2bf(kvv.y), f2bf(kvv.z), f2bf(kvv.w) };
        *(short4v*)&img[r * 256 + ((c4 * 2) ^ ((r & 7) << 4))] = ks;
        // V image (transposed): (kk=r, d) at byte 16384 + d*128 + ((2r)^((d&7)<<4))
        float4 vv = *(const float4*)(Vb + (size_t)r * ND + c4);
        float vf[4] = { vv.x, vv.y, vv.z, vv.w };
#pragma unroll
        for (int di = 0; di < 4; ++di) {
            int d = c4 + di;
            *(short*)&img[16384 + d * 128 + ((r * 2) ^ ((d & 7) << 4))] = f2bf(vf[di]);
        }
    }
    __syncthreads();
    float4* dst = (float4*)(ws + (size_t)(b * NT + t) * IMGB);
    const float4* srcl = (const float4*)img;
#pragma unroll
    for (int j = 0; j < 8; ++j)
        dst[j * 256 + tid] = srcl[j * 256 + tid];
}

// ---------------- main attention kernel ----------------
__global__ __launch_bounds__(256, 1)
void sdpa_fwd(const float* __restrict__ Qg, const uint8_t* __restrict__ ws,
              float* __restrict__ Og) {
    __shared__ __align__(16) uint8_t kv[2][IMGB];   // double-buffered tile images

    const int tid  = threadIdx.x;
    const int w    = tid >> 6;
    const int lane = tid & 63;
    const int lr_  = lane & 31;       // q-col (QK) / d-col (PV) index
    const int hi   = lane >> 5;
    const int xr   = (lane & 7) << 4; // LDS XOR swizzle for this lane's rows

    // block remap: same-batch blocks land on the same XCD (gid%8 constant)
    const int gid  = blockIdx.x;                     // 0..255
    const int b    = (gid & 7) * 2 + ((gid >> 3) & 1);
    const int qblk = gid >> 4;                       // 0..15
    const int q0w  = qblk * 128 + w * 32;

    // Q fragments: qf[dc] = Q[q0w + lr_][dc*16 + hi*8 + 0..7] * QSC
    bf16x8 qf[8];
    {
        const float* qrow = Qg + ((size_t)b * NS + q0w + lr_) * ND;
#pragma unroll
        for (int dc = 0; dc < 8; ++dc) {
            const float4* p = (const float4*)(qrow + dc * 16 + hi * 8);
            float4 x0 = p[0], x1 = p[1];
            bf16x8 f;
            f[0] = f2bf(x0.x * QSC); f[1] = f2bf(x0.y * QSC);
            f[2] = f2bf(x0.z * QSC); f[3] = f2bf(x0.w * QSC);
            f[4] = f2bf(x1.x * QSC); f[5] = f2bf(x1.y * QSC);
            f[6] = f2bf(x1.z * QSC); f[7] = f2bf(x1.w * QSC);
            qf[dc] = f;
        }
    }

    f32x16 acc[4];
#pragma unroll
    for (int n = 0; n < 4; ++n)
#pragma unroll
        for (int r = 0; r < 16; ++r) acc[n][r] = 0.f;
    float m_run = -__builtin_inff();
    float l_run = 0.f;

    const uint8_t* wsb = ws + (size_t)b * NT * IMGB;

    auto stage = [&](int bfi, int t) {
        const uint8_t* src = wsb + (size_t)t * IMGB + (size_t)(w * 8192 + lane * 16);
        uint8_t* dst = &kv[bfi][w * 8192];
#pragma unroll
        for (int it = 0; it < 8; ++it)
            gll16(src + it * 1024, dst + it * 1024);
    };

    // per-lane LDS base addresses (low bits hold the XOR'd column part)
    const int kbase = lr_ * 256 + ((hi * 16) ^ xr);
    const int vbase = 16384 + lr_ * 128 + ((hi * 16) ^ xr);

    int buf = 0;
    stage(0, 0);
    __syncthreads();

    for (int t = 0; t < NT; ++t) {
        if (t + 1 < NT) stage(buf ^ 1, t + 1);   // async prefetch next tile

        const uint8_t* img = kv[buf];

        // ---- S^T = K * Q^T : 2 kk-blocks of 32, 8 d-chunks of 16 ----
        f32x16 s0, s1;
#pragma unroll
        for (int r = 0; r < 16; ++r) { s0[r] = 0.f; s1[r] = 0.f; }
        __builtin_amdgcn_s_setprio(1);
#pragma unroll
        for (int dc = 0; dc < 8; ++dc) {
            const uint8_t* ka = img + (kbase ^ (dc * 32));
            bf16x8 k0 = *(const bf16x8*)ka;
            bf16x8 k1 = *(const bf16x8*)(ka + 8192);
            s0 = __builtin_amdgcn_mfma_f32_32x32x16_bf16(k0, qf[dc], s0, 0, 0, 0);
            s1 = __builtin_amdgcn_mfma_f32_32x32x16_bf16(k1, qf[dc], s1, 0, 0, 0);
        }
        __builtin_amdgcn_s_setprio(0);

        // ---- in-register online softmax (exp2 domain) ----
        // lane holds P[q=lr_][k = kb*32 + (r&3) + 8*(r>>2) + 4*hi]
        float tmax = -__builtin_inff();
#pragma unroll
        for (int r = 0; r < 16; ++r) tmax = fmaxf(tmax, fmaxf(s0[r], s1[r]));
        float tm = fmaxf(tmax, __shfl_xor(tmax, 32));

        if (__any(tm > m_run + 8.0f)) {          // defer-max (T13)
            float m_new = fmaxf(m_run, tm);
            float alpha = EXP2F(m_run - m_new);
            m_run = m_new;
            l_run *= alpha;
            float af[16];
#pragma unroll
            for (int r = 0; r < 16; ++r)
                af[r] = __shfl(alpha, (r & 3) + 8 * (r >> 2) + 4 * hi);
#pragma unroll
            for (int n = 0; n < 4; ++n)
#pragma unroll
                for (int r = 0; r < 16; ++r) acc[n][r] *= af[r];
        }

        float pv0[16], pv1[16], ts = 0.f;
#pragma unroll
        for (int r = 0; r < 16; ++r) {
            pv0[r] = EXP2F(s0[r] - m_run); ts += pv0[r];
            pv1[r] = EXP2F(s1[r] - m_run); ts += pv1[r];
        }
        l_run += ts + __shfl_xor(ts, 32);

        // ---- P -> bf16 A-fragments: 16 cvt_pk + shfl_xor(32) relayout ----
        int W[16];
#define PK(dst, x, y) asm("v_cvt_pk_bf16_f32 %0, %1, %2" : "=v"(dst) : "v"(x), "v"(y))
        PK(W[0],  pv0[0],  pv0[1]);  PK(W[1],  pv0[2],  pv0[3]);
        PK(W[2],  pv0[4],  pv0[5]);  PK(W[3],  pv0[6],  pv0[7]);
        PK(W[4],  pv0[8],  pv0[9]);  PK(W[5],  pv0[10], pv0[11]);
        PK(W[6],  pv0[12], pv0[13]); PK(W[7],  pv0[14], pv0[15]);
        PK(W[8],  pv1[0],  pv1[1]);  PK(W[9],  pv1[2],  pv1[3]);
        PK(W[10], pv1[4],  pv1[5]);  PK(W[11], pv1[6],  pv1[7]);
        PK(W[12], pv1[8],  pv1[9]);  PK(W[13], pv1[10], pv1[11]);
        PK(W[14], pv1[12], pv1[13]); PK(W[15], pv1[14], pv1[15]);
#undef PK
        bf16x8 pa[4];
#pragma unroll
        for (int g = 0; g < 4; ++g) {   // pa[g] covers k in [16g, 16g+16)
            int W0 = W[g * 4 + 0], W1 = W[g * 4 + 1];
            int W2 = W[g * 4 + 2], W3 = W[g * 4 + 3];
            int X0 = __shfl_xor(W0, 32), X1 = __shfl_xor(W1, 32);
            int X2 = __shfl_xor(W2, 32), X3 = __shfl_xor(W3, 32);
            int4v A;
            A[0] = hi ? X2 : W0;   // k = 16g + 8hi + {0,1}
            A[1] = hi ? X3 : W1;   // k = 16g + 8hi + {2,3}
            A[2] = hi ? W2 : X0;   // k = 16g + 8hi + {4,5}
            A[3] = hi ? W3 : X1;   // k = 16g + 8hi + {6,7}
            pa[g] = __builtin_bit_cast(bf16x8, A);
        }

        // ---- O += P * V : 4 d-blocks of 32, 4 k-chunks of 16 ----
        __builtin_amdgcn_s_setprio(1);
#pragma unroll
        for (int n = 0; n < 4; ++n) {
#pragma unroll
            for (int kc = 0; kc < 4; ++kc) {
                bf16x8 vf = *(const bf16x8*)(img + ((vbase ^ (kc * 32)) + n * 4096));
                acc[n] = __builtin_amdgcn_mfma_f32_32x32x16_bf16(pa[kc], vf, acc[n], 0, 0, 0);
            }
        }
        __builtin_amdgcn_s_setprio(0);

        __syncthreads();   // next tile's image now resident
        buf ^= 1;
    }

    // ---- epilogue: normalize and store fp32 ----
    float li[16];
#pragma unroll
    for (int r = 0; r < 16; ++r)
        li[r] = 1.f / __shfl(l_run, (r & 3) + 8 * (r >> 2) + 4 * hi);
    float* ob = Og + ((size_t)b * NS + q0w) * ND + lr_;
#pragma unroll
    for (int r = 0; r < 16; ++r) {
        int row = (r & 3) + 8 * (r >> 2) + 4 * hi;
#pragma unroll
        for (int n = 0; n < 4; ++n)
            ob[(size_t)row * ND + n * 32] = acc[n][r] * li[r];
    }
}

extern "C" void kernel_launch(void* const* d_in, const int* in_sizes, int n_in,
                              void* d_out, int out_size, void* d_ws, size_t ws_size,
                              hipStream_t stream) {
    const float* Q = (const float*)d_in[0];
    const float* K = (const float*)d_in[1];
    const float* V = (const float*)d_in[2];
    float* O = (float*)d_out;
    (void)in_sizes; (void)n_in; (void)out_size; (void)ws_size;
    uint8_t* ws = (uint8_t*)d_ws;
    prep_kv<<<dim3(NT, NB), 256, 0, stream>>>(K, V, ws);
    sdpa_fwd<<<dim3(NB * NS / 128, 1), 256, 0, stream>>>(Q, ws, O);
}

// Round 6
// 62.560 us; speedup vs baseline: 3.3189x; 1.2129x over previous
//
#include <hip/hip_runtime.h>
#include <hip/hip_bf16.h>

// Scaled dot-product attention, B=16, S=2048, D=128, fp32 in/out.
//  prep_kv: K,V -> bf16 once; per-tile pre-swizzled LDS images in d_ws.
//  sdpa_fwd: 32x32 MFMA flash attention, 8 waves = 4 q-groups x 2 KV-halves
//  (in-block split-KV for 2 waves/SIMD), swapped QK^T, in-register softmax
//  (cvt_pk + shfl_xor(32)), linear global_load_lds double-buffered staging,
//  online-softmax merge of the two halves through LDS at the end.

#define NB 16
#define NS 2048
#define ND 128
#define KVBLK 64
#define NT (NS / KVBLK)          // 32 KV tiles per batch
#define NHT (NT / 2)             // 16 tiles per half
#define IMGB 32768               // per-tile image: K 16KB + V 16KB
// Q pre-scale: (1/sqrt(128)) * log2(e)  -> softmax in exp2 domain
#define QSC (0.08838834764831845f * 1.4426950408889634f)

typedef __attribute__((ext_vector_type(8))) short bf16x8;
typedef __attribute__((ext_vector_type(4))) short short4v;
typedef __attribute__((ext_vector_type(16))) float f32x16;
typedef __attribute__((ext_vector_type(4))) int int4v;

__device__ __forceinline__ short f2bf(float f) {
    unsigned u = __builtin_bit_cast(unsigned, f);
    return (short)((u + 0x7fffu + ((u >> 16) & 1u)) >> 16);  // RNE
}

#if __has_builtin(__builtin_amdgcn_exp2f)
#define EXP2F(x) __builtin_amdgcn_exp2f(x)
#else
#define EXP2F(x) __expf((x) * 0.6931471805599453f)
#endif

__device__ __forceinline__ void gll16(const void* g, void* l) {
    __builtin_amdgcn_global_load_lds(
        (const __attribute__((address_space(1))) uint32_t*)g,
        (__attribute__((address_space(3))) uint32_t*)l, 16, 0, 0);
}

// ---------------- pre-pass: build swizzled bf16 tile images ----------------
__global__ __launch_bounds__(256, 2)
void prep_kv(const float* __restrict__ Kg, const float* __restrict__ Vg,
             uint8_t* __restrict__ ws) {
    __shared__ __align__(16) uint8_t img[IMGB];
    const int tid = threadIdx.x;
    const int t = blockIdx.x, b = blockIdx.y;
    const float* Kb = Kg + ((size_t)b * NS + (size_t)t * KVBLK) * ND;
    const float* Vb = Vg + ((size_t)b * NS + (size_t)t * KVBLK) * ND;
#pragma unroll
    for (int it = 0; it < 8; ++it) {
        int idx = it * 256 + tid;
        int r  = idx >> 5;            // kv row 0..63
        int c4 = (idx & 31) << 2;     // d 0..124 step 4
        // K image: element (r, d) at byte r*256 + ((2d) ^ ((r&7)<<4))
        float4 kvv = *(const float4*)(Kb + (size_t)r * ND + c4);
        short4v ks = { f2bf(kvv.x), f2bf(kvv.y), f2bf(kvv.z), f2bf(kvv.w) };
        *(short4v*)&img[r * 256 + ((c4 * 2) ^ ((r & 7) << 4))] = ks;
        // V image (transposed): (kk=r, d) at byte 16384 + d*128 + ((2r)^((d&7)<<4))
        float4 vv = *(const float4*)(Vb + (size_t)r * ND + c4);
        float vf[4] = { vv.x, vv.y, vv.z, vv.w };
#pragma unroll
        for (int di = 0; di < 4; ++di) {
            int d = c4 + di;
            *(short*)&img[16384 + d * 128 + ((r * 2) ^ ((d & 7) << 4))] = f2bf(vf[di]);
        }
    }
    __syncthreads();
    float4* dst = (float4*)(ws + (size_t)(b * NT + t) * IMGB);
    const float4* srcl = (const float4*)img;
#pragma unroll
    for (int j = 0; j < 8; ++j)
        dst[j * 256 + tid] = srcl[j * 256 + tid];
}

// ---------------- main attention kernel ----------------
__global__ __launch_bounds__(512, 2)
void sdpa_fwd(const float* __restrict__ Qg, const uint8_t* __restrict__ ws,
              float* __restrict__ Og) {
    // [buf][kv-half] double-buffered tile images: 128 KB
    __shared__ __align__(16) uint8_t kv[2][2][IMGB];

    const int tid  = threadIdx.x;
    const int w    = tid >> 6;        // 0..7
    const int wq   = w & 3;           // q-group 0..3
    const int wh   = w >> 2;          // KV half 0/1
    const int lane = tid & 63;
    const int lr_  = lane & 31;       // q-col (QK) / d-col (PV) index
    const int hi   = lane >> 5;
    const int xr   = (lane & 7) << 4; // LDS XOR swizzle for this lane's rows

    // block remap: same-batch blocks land on the same XCD (gid%8 constant)
    const int gid  = blockIdx.x;                     // 0..255
    const int b    = (gid & 7) * 2 + ((gid >> 3) & 1);
    const int qblk = gid >> 4;                       // 0..15
    const int q0w  = qblk * 128 + wq * 32;

    // Q fragments: qf[dc] = Q[q0w + lr_][dc*16 + hi*8 + 0..7] * QSC
    bf16x8 qf[8];
    {
        const float* qrow = Qg + ((size_t)b * NS + q0w + lr_) * ND;
#pragma unroll
        for (int dc = 0; dc < 8; ++dc) {
            const float4* p = (const float4*)(qrow + dc * 16 + hi * 8);
            float4 x0 = p[0], x1 = p[1];
            bf16x8 f;
            f[0] = f2bf(x0.x * QSC); f[1] = f2bf(x0.y * QSC);
            f[2] = f2bf(x0.z * QSC); f[3] = f2bf(x0.w * QSC);
            f[4] = f2bf(x1.x * QSC); f[5] = f2bf(x1.y * QSC);
            f[6] = f2bf(x1.z * QSC); f[7] = f2bf(x1.w * QSC);
            qf[dc] = f;
        }
    }

    f32x16 acc[4];
#pragma unroll
    for (int n = 0; n < 4; ++n)
#pragma unroll
        for (int r = 0; r < 16; ++r) acc[n][r] = 0.f;
    float m_run = -__builtin_inff();
    float l_run = 0.f;

    const uint8_t* wsb = ws + (size_t)b * NT * IMGB;

    // stage tile (wh*NHT + it) into kv[bfi][wh]; 4 waves x 8KB per image
    auto stage = [&](int bfi, int it) {
        const uint8_t* src = wsb + (size_t)(wh * NHT + it) * IMGB
                                 + (size_t)(wq * 8192 + lane * 16);
        uint8_t* dst = &kv[bfi][wh][wq * 8192];
#pragma unroll
        for (int i = 0; i < 8; ++i)
            gll16(src + i * 1024, dst + i * 1024);
    };

    // per-lane LDS base addresses (low bits hold the XOR'd column part)
    const int kbase = lr_ * 256 + ((hi * 16) ^ xr);
    const int vbase = 16384 + lr_ * 128 + ((hi * 16) ^ xr);

    int buf = 0;
    stage(0, 0);
    __syncthreads();

    for (int t = 0; t < NHT; ++t) {
        if (t + 1 < NHT) stage(buf ^ 1, t + 1);   // async prefetch next tile

        const uint8_t* img = kv[buf][wh];

        // ---- S^T = K * Q^T : 2 kk-blocks of 32, 8 d-chunks of 16 ----
        f32x16 s0, s1;
#pragma unroll
        for (int r = 0; r < 16; ++r) { s0[r] = 0.f; s1[r] = 0.f; }
        __builtin_amdgcn_s_setprio(1);
#pragma unroll
        for (int dc = 0; dc < 8; ++dc) {
            const uint8_t* ka = img + (kbase ^ (dc * 32));
            bf16x8 k0 = *(const bf16x8*)ka;
            bf16x8 k1 = *(const bf16x8*)(ka + 8192);
            s0 = __builtin_amdgcn_mfma_f32_32x32x16_bf16(k0, qf[dc], s0, 0, 0, 0);
            s1 = __builtin_amdgcn_mfma_f32_32x32x16_bf16(k1, qf[dc], s1, 0, 0, 0);
        }
        __builtin_amdgcn_s_setprio(0);

        // ---- in-register online softmax (exp2 domain) ----
        // lane holds P[q=lr_][k = kb*32 + (r&3) + 8*(r>>2) + 4*hi]
        float tmax = -__builtin_inff();
#pragma unroll
        for (int r = 0; r < 16; ++r) tmax = fmaxf(tmax, fmaxf(s0[r], s1[r]));
        float tm = fmaxf(tmax, __shfl_xor(tmax, 32));

        if (__any(tm > m_run + 8.0f)) {          // defer-max (T13)
            float m_new = fmaxf(m_run, tm);
            float alpha = EXP2F(m_run - m_new);
            m_run = m_new;
            l_run *= alpha;
            float af[16];
#pragma unroll
            for (int r = 0; r < 16; ++r)
                af[r] = __shfl(alpha, (r & 3) + 8 * (r >> 2) + 4 * hi);
#pragma unroll
            for (int n = 0; n < 4; ++n)
#pragma unroll
                for (int r = 0; r < 16; ++r) acc[n][r] *= af[r];
        }

        float pv0[16], pv1[16], ts = 0.f;
#pragma unroll
        for (int r = 0; r < 16; ++r) {
            pv0[r] = EXP2F(s0[r] - m_run); ts += pv0[r];
            pv1[r] = EXP2F(s1[r] - m_run); ts += pv1[r];
        }
        l_run += ts + __shfl_xor(ts, 32);

        // ---- P -> bf16 A-fragments: 16 cvt_pk + shfl_xor(32) relayout ----
        int W[16];
#define PK(dst, x, y) asm("v_cvt_pk_bf16_f32 %0, %1, %2" : "=v"(dst) : "v"(x), "v"(y))
        PK(W[0],  pv0[0],  pv0[1]);  PK(W[1],  pv0[2],  pv0[3]);
        PK(W[2],  pv0[4],  pv0[5]);  PK(W[3],  pv0[6],  pv0[7]);
        PK(W[4],  pv0[8],  pv0[9]);  PK(W[5],  pv0[10], pv0[11]);
        PK(W[6],  pv0[12], pv0[13]); PK(W[7],  pv0[14], pv0[15]);
        PK(W[8],  pv1[0],  pv1[1]);  PK(W[9],  pv1[2],  pv1[3]);
        PK(W[10], pv1[4],  pv1[5]);  PK(W[11], pv1[6],  pv1[7]);
        PK(W[12], pv1[8],  pv1[9]);  PK(W[13], pv1[10], pv1[11]);
        PK(W[14], pv1[12], pv1[13]); PK(W[15], pv1[14], pv1[15]);
#undef PK
        bf16x8 pa[4];
#pragma unroll
        for (int g = 0; g < 4; ++g) {   // pa[g] covers k in [16g, 16g+16)
            int W0 = W[g * 4 + 0], W1 = W[g * 4 + 1];
            int W2 = W[g * 4 + 2], W3 = W[g * 4 + 3];
            int X0 = __shfl_xor(W0, 32), X1 = __shfl_xor(W1, 32);
            int X2 = __shfl_xor(W2, 32), X3 = __shfl_xor(W3, 32);
            int4v A;
            A[0] = hi ? X2 : W0;   // k = 16g + 8hi + {0,1}
            A[1] = hi ? X3 : W1;   // k = 16g + 8hi + {2,3}
            A[2] = hi ? W2 : X0;   // k = 16g + 8hi + {4,5}
            A[3] = hi ? W3 : X1;   // k = 16g + 8hi + {6,7}
            pa[g] = __builtin_bit_cast(bf16x8, A);
        }

        // ---- O += P * V : 4 d-blocks of 32, 4 k-chunks of 16 ----
        __builtin_amdgcn_s_setprio(1);
#pragma unroll
        for (int n = 0; n < 4; ++n) {
#pragma unroll
            for (int kc = 0; kc < 4; ++kc) {
                bf16x8 vf = *(const bf16x8*)(img + ((vbase ^ (kc * 32)) + n * 4096));
                acc[n] = __builtin_amdgcn_mfma_f32_32x32x16_bf16(pa[kc], vf, acc[n], 0, 0, 0);
            }
        }
        __builtin_amdgcn_s_setprio(0);

        __syncthreads();   // next tile's images now resident (both halves)
        buf ^= 1;
    }

    // ---- merge the two KV halves (online-softmax combine) and store ----
    // scr layout: per upper wave wq, 64 lanes x 66 f32 (stride 66 -> 2-way banks)
    float* scr = (float*)&kv[0][0][0];
    const int sbase = wq * 4224 + lane * 66;
    if (wh == 1) {
#pragma unroll
        for (int n = 0; n < 4; ++n)
#pragma unroll
            for (int r = 0; r < 16; ++r) scr[sbase + n * 16 + r] = acc[n][r];
        scr[sbase + 64] = m_run;
        scr[sbase + 65] = l_run;
    }
    __syncthreads();
    if (wh == 0) {
        float m1 = scr[sbase + 64], l1 = scr[sbase + 65];
        float mm = fmaxf(m_run, m1);
        float a0 = EXP2F(m_run - mm), a1 = EXP2F(m1 - mm);
        float lc = l_run * a0 + l1 * a1;
        float af0[16], af1[16], li[16];
#pragma unroll
        for (int r = 0; r < 16; ++r) {
            int row = (r & 3) + 8 * (r >> 2) + 4 * hi;
            af0[r] = __shfl(a0, row);
            af1[r] = __shfl(a1, row);
            li[r] = 1.f / __shfl(lc, row);
        }
        float* ob = Og + ((size_t)b * NS + q0w) * ND + lr_;
#pragma unroll
        for (int r = 0; r < 16; ++r) {
            int row = (r & 3) + 8 * (r >> 2) + 4 * hi;
#pragma unroll
            for (int n = 0; n < 4; ++n)
                ob[(size_t)row * ND + n * 32] =
                    (acc[n][r] * af0[r] + scr[sbase + n * 16 + r] * af1[r]) * li[r];
        }
    }
}

extern "C" void kernel_launch(void* const* d_in, const int* in_sizes, int n_in,
                              void* d_out, int out_size, void* d_ws, size_t ws_size,
                              hipStream_t stream) {
    const float* Q = (const float*)d_in[0];
    const float* K = (const float*)d_in[1];
    const float* V = (const float*)d_in[2];
    float* O = (float*)d_out;
    (void)in_sizes; (void)n_in; (void)out_size; (void)ws_size;
    uint8_t* ws = (uint8_t*)d_ws;
    prep_kv<<<dim3(NT, NB), 256, 0, stream>>>(K, V, ws);
    sdpa_fwd<<<dim3(NB * NS / 128, 1), 512, 0, stream>>>(Q, ws, O);
}